// Round 1
// baseline (1810.399 us; speedup 1.0000x reference)
//
#include <hip/hip_runtime.h>
#include <math.h>

#define N_NODES 50000
#define N_EDGES 400000
#define N_GRAPHS 512
#define TBL 2048
#define EPSBN 1e-5f

__device__ __forceinline__ float softplusf(float x) {
  return fmaxf(x, 0.0f) + log1pf(expf(-fabsf(x)));
}
__device__ __forceinline__ float sigmoidf(float x) {
  return 1.0f / (1.0f + expf(-x));
}

// h = atom @ W_emb + b_emb   [N,92]@[92,64]
__global__ void k_emb(const float* __restrict__ atom,
                      const float* __restrict__ Wemb,
                      const float* __restrict__ bemb,
                      float* __restrict__ h) {
  __shared__ float sW[92 * 64];
  for (int i = threadIdx.x; i < 92 * 64; i += blockDim.x) sW[i] = Wemb[i];
  __syncthreads();
  const int wave = threadIdx.x >> 6, lane = threadIdx.x & 63;
  const int wpb = blockDim.x >> 6;
  const int nw = wpb * gridDim.x;
  const float bb = bemb[lane];
  for (int n = blockIdx.x * wpb + wave; n < N_NODES; n += nw) {
    const float* ar = atom + (size_t)n * 92;
    float acc = bb;
#pragma unroll
    for (int k = 0; k < 92; ++k) acc = fmaf(ar[k], sW[k * 64 + lane], acc);
    h[(size_t)n * 64 + lane] = acc;
  }
}

// PQ[m][n][j]: m=0: h@Wi[0:64] (P_i), m=1: h@Wi[64:128] (Q_i), m=2/3 same for Wu.
__global__ void k_pq(const float* __restrict__ h,
                     const float* __restrict__ Wi_l,
                     const float* __restrict__ Wu_l,
                     float* __restrict__ PQ) {
  __shared__ float sW[2][64 * 64];  // 32 KB
  const int wave = threadIdx.x >> 6, lane = threadIdx.x & 63;
  const int wpb = blockDim.x >> 6;
  const int nw = wpb * gridDim.x;
  for (int ph = 0; ph < 2; ++ph) {
    const float* W = ph ? Wu_l : Wi_l;
    __syncthreads();
    for (int i = threadIdx.x; i < 64 * 64; i += blockDim.x) {
      sW[0][i] = W[i];             // rows 0..63  (src part)
      sW[1][i] = W[64 * 64 + i];   // rows 64..127 (dst part)
    }
    __syncthreads();
    float* P = PQ + (size_t)(2 * ph) * N_NODES * 64;
    float* Q = PQ + (size_t)(2 * ph + 1) * N_NODES * 64;
    for (int n = blockIdx.x * wpb + wave; n < N_NODES; n += nw) {
      float hv = h[(size_t)n * 64 + lane];
      float a0 = 0.f, a1 = 0.f;
#pragma unroll
      for (int k = 0; k < 64; ++k) {
        float hk = __shfl(hv, k);
        a0 = fmaf(hk, sW[0][k * 64 + lane], a0);
        a1 = fmaf(hk, sW[1][k * 64 + lane], a1);
      }
      P[(size_t)n * 64 + lane] = a0;
      Q[(size_t)n * 64 + lane] = a1;
    }
  }
}

// tbl[t][j] = sum_k exp(-gamma*(d_t - c_k)^2) * W[128+k][j], for Wi (first TBL*64) and Wu.
__global__ void k_tbl(const float* __restrict__ Wi_l,
                      const float* __restrict__ Wu_l,
                      float* __restrict__ tbl) {
  const int wave = threadIdx.x >> 6, lane = threadIdx.x & 63;
  const int t = blockIdx.x * (blockDim.x >> 6) + wave;
  if (t >= TBL) return;
  const float d = 8.0f * (float)t / (float)(TBL - 1);
  float gi_ = 0.f, gu_ = 0.f;
#pragma unroll
  for (int k = 0; k < 32; ++k) {
    float c = 8.0f * (float)k / 31.0f;
    float dd = d - c;
    float r = expf(-3.875f * dd * dd);
    gi_ = fmaf(r, Wi_l[(128 + k) * 64 + lane], gi_);
    gu_ = fmaf(r, Wu_l[(128 + k) * 64 + lane], gu_);
  }
  tbl[(size_t)t * 64 + lane] = gi_;
  tbl[(size_t)TBL * 64 + (size_t)t * 64 + lane] = gu_;
}

__device__ __forceinline__ void edge_pre(int e, int lane,
                                         const int* __restrict__ src,
                                         const int* __restrict__ dst,
                                         const float* __restrict__ bond,
                                         const float* __restrict__ PQ,
                                         const float* __restrict__ tbl,
                                         float& yg, float& yu, int& dnode) {
  const int s = src[e];
  const int d2 = dst[e];
  const float d = bond[e];
  float f = d * ((float)(TBL - 1) / 8.0f);
  f = fminf(fmaxf(f, 0.0f), (float)(TBL - 1));
  int i0 = (int)f;
  if (i0 > TBL - 2) i0 = TBL - 2;
  const float fr = f - (float)i0;
  const float* tg = tbl + (size_t)i0 * 64 + lane;
  const float* tu = tg + (size_t)TBL * 64;
  const float rg = fmaf(fr, tg[64] - tg[0], tg[0]);
  const float ru = fmaf(fr, tu[64] - tu[0], tu[0]);
  yg = PQ[(size_t)s * 64 + lane] + PQ[((size_t)N_NODES + d2) * 64 + lane] + rg;
  yu = PQ[((size_t)2 * N_NODES + s) * 64 + lane] +
       PQ[((size_t)3 * N_NODES + d2) * 64 + lane] + ru;
  dnode = d2;
}

// Pass 1: column sums / sumsq of gate_pre and upd_pre over all edges.
__global__ void k_edge_stats(const int* __restrict__ src,
                             const int* __restrict__ dst,
                             const float* __restrict__ bond,
                             const float* __restrict__ PQ,
                             const float* __restrict__ tbl,
                             float* __restrict__ stats) {
  const int wave = threadIdx.x >> 6, lane = threadIdx.x & 63;
  const int wpb = blockDim.x >> 6;
  const int nw = wpb * gridDim.x;
  float sg = 0.f, qg = 0.f, su = 0.f, qu = 0.f;
  for (int e = blockIdx.x * wpb + wave; e < N_EDGES; e += nw) {
    float yg, yu; int dn;
    edge_pre(e, lane, src, dst, bond, PQ, tbl, yg, yu, dn);
    sg += yg; qg = fmaf(yg, yg, qg);
    su += yu; qu = fmaf(yu, yu, qu);
  }
  __shared__ float red[4][4][64];
  red[0][wave][lane] = sg;
  red[1][wave][lane] = qg;
  red[2][wave][lane] = su;
  red[3][wave][lane] = qu;
  __syncthreads();
  // wave w reduces quantity w across the 4 waves
  float v = red[wave][0][lane] + red[wave][1][lane] + red[wave][2][lane] + red[wave][3][lane];
  atomicAdd(&stats[wave * 64 + lane], v);
}

// BN scale/shift for gate & upd. (bi/bu cancel exactly under BN.)
__global__ void k_fin_gu(const float* __restrict__ stats,
                         const float* __restrict__ gi_l, const float* __restrict__ bti_l,
                         const float* __restrict__ gu_l, const float* __restrict__ btu_l,
                         float* __restrict__ coefs) {
  const int j = threadIdx.x;
  const float invE = 1.0f / (float)N_EDGES;
  float m = stats[j] * invE;
  float v = stats[64 + j] * invE - m * m;
  float a = gi_l[j] * rsqrtf(v + EPSBN);
  coefs[j] = a;
  coefs[64 + j] = fmaf(-m, a, bti_l[j]);
  m = stats[128 + j] * invE;
  v = stats[192 + j] * invE - m * m;
  a = gu_l[j] * rsqrtf(v + EPSBN);
  coefs[128 + j] = a;
  coefs[192 + j] = fmaf(-m, a, btu_l[j]);
}

// Pass 2: recompute, apply BN+activations, scatter-add msg into agg[dst].
__global__ void k_edge_apply(const int* __restrict__ src,
                             const int* __restrict__ dst,
                             const float* __restrict__ bond,
                             const float* __restrict__ PQ,
                             const float* __restrict__ tbl,
                             const float* __restrict__ coefs,
                             float* __restrict__ agg) {
  const int wave = threadIdx.x >> 6, lane = threadIdx.x & 63;
  const int wpb = blockDim.x >> 6;
  const int nw = wpb * gridDim.x;
  const float ag = coefs[lane], bg = coefs[64 + lane];
  const float au = coefs[128 + lane], bu = coefs[192 + lane];
  for (int e = blockIdx.x * wpb + wave; e < N_EDGES; e += nw) {
    float yg, yu; int dn;
    edge_pre(e, lane, src, dst, bond, PQ, tbl, yg, yu, dn);
    const float gate = sigmoidf(fmaf(ag, yg, bg));
    const float upd = softplusf(fmaf(au, yu, bu));
    atomicAdd(&agg[(size_t)dn * 64 + lane], gate * upd);
  }
}

__global__ void k_agg_stats(const float* __restrict__ agg, float* __restrict__ stats) {
  const int wave = threadIdx.x >> 6, lane = threadIdx.x & 63;
  const int wpb = blockDim.x >> 6;
  const int nw = wpb * gridDim.x;
  float s = 0.f, q = 0.f;
  for (int n = blockIdx.x * wpb + wave; n < N_NODES; n += nw) {
    float v = agg[(size_t)n * 64 + lane];
    s += v; q = fmaf(v, v, q);
  }
  __shared__ float red[2][4][64];
  red[0][wave][lane] = s;
  red[1][wave][lane] = q;
  __syncthreads();
  if (wave < 2) {
    float v = red[wave][0][lane] + red[wave][1][lane] + red[wave][2][lane] + red[wave][3][lane];
    atomicAdd(&stats[256 + wave * 64 + lane], v);
  }
}

__global__ void k_fin_agg(const float* __restrict__ stats,
                          const float* __restrict__ gbn_l, const float* __restrict__ bbn_l,
                          float* __restrict__ coefs) {
  const int j = threadIdx.x;
  const float invN = 1.0f / (float)N_NODES;
  float m = stats[256 + j] * invN;
  float v = stats[320 + j] * invN - m * m;
  float a = gbn_l[j] * rsqrtf(v + EPSBN);
  coefs[256 + j] = a;
  coefs[320 + j] = fmaf(-m, a, bbn_l[j]);
}

// h = softplus(h + BN(agg))
__global__ void k_hupd(float* __restrict__ h, const float* __restrict__ agg,
                       const float* __restrict__ coefs) {
  const int stride = blockDim.x * gridDim.x;
  for (int i = blockIdx.x * blockDim.x + threadIdx.x; i < N_NODES * 64; i += stride) {
    const int j = i & 63;
    float x = h[i] + fmaf(coefs[256 + j], agg[i], coefs[320 + j]);
    h[i] = softplusf(x);
  }
}

__global__ void k_pool(const float* __restrict__ h, const int* __restrict__ gid,
                       float* __restrict__ pooled, float* __restrict__ counts) {
  const int wave = threadIdx.x >> 6, lane = threadIdx.x & 63;
  const int wpb = blockDim.x >> 6;
  const int nw = wpb * gridDim.x;
  for (int n = blockIdx.x * wpb + wave; n < N_NODES; n += nw) {
    const int g = gid[n];
    atomicAdd(&pooled[(size_t)g * 64 + lane], h[(size_t)n * 64 + lane]);
    if (lane == 0) atomicAdd(&counts[g], 1.0f);
  }
}

__global__ void k_final(const float* __restrict__ pooled, const float* __restrict__ counts,
                        const float* __restrict__ Wfc, const float* __restrict__ bfc,
                        const float* __restrict__ Wout, const float* __restrict__ bout,
                        float* __restrict__ out) {
  __shared__ float f1[64];
  __shared__ float red[128];
  const int g = blockIdx.x, t = threadIdx.x;
  if (t < 64) {
    const float c = fmaxf(counts[g], 1.0f);
    f1[t] = softplusf(pooled[(size_t)g * 64 + t] / c);
  }
  __syncthreads();
  float acc = bfc[t];
#pragma unroll
  for (int k = 0; k < 64; ++k) acc = fmaf(f1[k], Wfc[k * 128 + t], acc);
  red[t] = softplusf(softplusf(acc)) * Wout[t];
  __syncthreads();
  for (int s2 = 64; s2 > 0; s2 >>= 1) {
    if (t < s2) red[t] += red[t + s2];
    __syncthreads();
  }
  if (t == 0) out[g] = red[0] + bout[0];
}

extern "C" void kernel_launch(void* const* d_in, const int* in_sizes, int n_in,
                              void* d_out, int out_size, void* d_ws, size_t ws_size,
                              hipStream_t stream) {
  const float* atom = (const float*)d_in[0];
  const float* bond = (const float*)d_in[1];
  const int* src = (const int*)d_in[2];
  const int* dst = (const int*)d_in[3];
  const int* gid = (const int*)d_in[4];
  const float* Wemb = (const float*)d_in[5];
  const float* bemb = (const float*)d_in[6];
  const float* Wi = (const float*)d_in[7];
  // d_in[8] = bi  — cancels under BN (mean-shift), unused
  const float* gi = (const float*)d_in[9];
  const float* bti = (const float*)d_in[10];
  const float* Wu = (const float*)d_in[11];
  // d_in[12] = bu — cancels under BN, unused
  const float* gub = (const float*)d_in[13];
  const float* btu = (const float*)d_in[14];
  const float* gbn = (const float*)d_in[15];
  const float* bbn = (const float*)d_in[16];
  const float* Wfc = (const float*)d_in[17];
  const float* bfc = (const float*)d_in[18];
  const float* Wout = (const float*)d_in[19];
  const float* bout = (const float*)d_in[20];

  // workspace layout (floats): total ~19.5M floats ≈ 78 MB
  float* h = (float*)d_ws;                              // N*64
  float* PQ = h + (size_t)N_NODES * 64;                 // 4*N*64
  float* agg = PQ + (size_t)4 * N_NODES * 64;           // N*64
  float* tbl = agg + (size_t)N_NODES * 64;              // 2*TBL*64
  float* stats = tbl + (size_t)2 * TBL * 64;            // 384
  float* coefs = stats + 384;                           // 384
  float* pooled = coefs + 384;                          // G*64
  float* counts = pooled + (size_t)N_GRAPHS * 64;       // G

  k_emb<<<512, 256, 0, stream>>>(atom, Wemb, bemb, h);
  for (int l = 0; l < 3; ++l) {
    const float* Wi_l = Wi + (size_t)l * 160 * 64;
    const float* Wu_l = Wu + (size_t)l * 160 * 64;
    hipMemsetAsync(stats, 0, 384 * sizeof(float), stream);
    hipMemsetAsync(agg, 0, (size_t)N_NODES * 64 * sizeof(float), stream);
    k_pq<<<512, 256, 0, stream>>>(h, Wi_l, Wu_l, PQ);
    k_tbl<<<TBL / 4, 256, 0, stream>>>(Wi_l, Wu_l, tbl);
    k_edge_stats<<<1024, 256, 0, stream>>>(src, dst, bond, PQ, tbl, stats);
    k_fin_gu<<<1, 64, 0, stream>>>(stats, gi + l * 64, bti + l * 64,
                                   gub + l * 64, btu + l * 64, coefs);
    k_edge_apply<<<1024, 256, 0, stream>>>(src, dst, bond, PQ, tbl, coefs, agg);
    k_agg_stats<<<512, 256, 0, stream>>>(agg, stats);
    k_fin_agg<<<1, 64, 0, stream>>>(stats, gbn + l * 64, bbn + l * 64, coefs);
    k_hupd<<<1024, 256, 0, stream>>>(h, agg, coefs);
  }
  hipMemsetAsync(pooled, 0, (size_t)(N_GRAPHS * 64 + N_GRAPHS) * sizeof(float), stream);
  k_pool<<<512, 256, 0, stream>>>(h, gid, pooled, counts);
  k_final<<<N_GRAPHS, 128, 0, stream>>>(pooled, counts, Wfc, bfc, Wout, bout,
                                        (float*)d_out);
}

// Round 3
// 1791.396 us; speedup vs baseline: 1.0106x; 1.0106x over previous
//
#include <hip/hip_runtime.h>
#include <math.h>

#define N_NODES 50000
#define N_EDGES 400000
#define N_GRAPHS 512
#define TBL 2048
#define EPSBN 1e-5f

__device__ __forceinline__ float softplusf(float x) {
  return fmaxf(x, 0.0f) + log1pf(expf(-fabsf(x)));
}
__device__ __forceinline__ float sigmoidf(float x) {
  return 1.0f / (1.0f + expf(-x));
}
__device__ __forceinline__ void fma4(float4& acc, float s, const float4& w) {
  acc.x = fmaf(s, w.x, acc.x);
  acc.y = fmaf(s, w.y, acc.y);
  acc.z = fmaf(s, w.z, acc.z);
  acc.w = fmaf(s, w.w, acc.w);
}

// ---------------- h = atom @ W_emb + b_emb   [N,92]@[92,64] ----------------
// Tile of 32 nodes per block; atom rows staged into LDS (contiguous ->
// coalesced); W in LDS; thread = (nodegroup of 8) x (1 col).
__global__ void k_emb(const float* __restrict__ atom,
                      const float* __restrict__ Wemb,
                      const float* __restrict__ bemb,
                      float* __restrict__ h) {
  __shared__ float sW[92 * 64];   // [k][j] 23.5 KB
  __shared__ float sA[32 * 92];   // [nd][k] 11.5 KB
  const int tid = threadIdx.x;
  for (int i = tid; i < 92 * 64; i += 256) sW[i] = Wemb[i];

  const int t0 = blockIdx.x * 32;
  const int nt = min(32, N_NODES - t0);
  {
    const float* srcp = atom + (size_t)t0 * 92;
    const int tot = nt * 92;
    for (int i = tid; i < tot; i += 256) sA[i] = srcp[i];
  }
  __syncthreads();

  const int col = tid & 63;
  const int ng = tid >> 6;  // node subgroup 0..3 -> nodes ng*8..ng*8+7
  const float bb = bemb[col];
  float acc[8];
#pragma unroll
  for (int i = 0; i < 8; ++i) acc[i] = bb;

  for (int kc = 0; kc < 92; kc += 4) {
    const float w0 = sW[(kc + 0) * 64 + col];
    const float w1 = sW[(kc + 1) * 64 + col];
    const float w2 = sW[(kc + 2) * 64 + col];
    const float w3 = sW[(kc + 3) * 64 + col];
#pragma unroll
    for (int i = 0; i < 8; ++i) {
      const float4 a = *(const float4*)&sA[(ng * 8 + i) * 92 + kc];
      acc[i] = fmaf(a.x, w0, acc[i]);
      acc[i] = fmaf(a.y, w1, acc[i]);
      acc[i] = fmaf(a.z, w2, acc[i]);
      acc[i] = fmaf(a.w, w3, acc[i]);
    }
  }
#pragma unroll
  for (int i = 0; i < 8; ++i) {
    const int n = t0 + ng * 8 + i;
    if (n < N_NODES) h[(size_t)n * 64 + col] = acc[i];
  }
}

// ---------------- PA/PB = h @ [Wi|Wu] split by src/dst halves --------------
// PA[n][128] = [ h@Wi[0:64]   | h@Wu[0:64]   ]   (gathered by src)
// PB[n][128] = [ h@Wi[64:128] | h@Wu[64:128] ]   (gathered by dst)
// 32-node tile; weights in LDS (64 KB); thread owns 8 nodes x 4 packed cols.
__global__ void k_pq(const float* __restrict__ h,
                     const float* __restrict__ Wi_l,
                     const float* __restrict__ Wu_l,
                     float* __restrict__ PA,
                     float* __restrict__ PB) {
  __shared__ float sWA[64 * 128];  // [k][pc] pc: 0..63 Wi-src, 64..127 Wu-src
  __shared__ float sWB[64 * 128];  // [k][pc] pc: 0..63 Wi-dst, 64..127 Wu-dst
  __shared__ float sH[32 * 64];    // [nd][k]
  const int tid = threadIdx.x;

  for (int i = tid; i < 64 * 64; i += 256) {
    const int k = i >> 6, c = i & 63;
    sWA[k * 128 + c]      = Wi_l[k * 64 + c];
    sWA[k * 128 + 64 + c] = Wu_l[k * 64 + c];
    sWB[k * 128 + c]      = Wi_l[(64 + k) * 64 + c];
    sWB[k * 128 + 64 + c] = Wu_l[(64 + k) * 64 + c];
  }
  const int t0 = blockIdx.x * 32;
  const int nt = min(32, N_NODES - t0);
  {
    const float4* srcp = (const float4*)(h + (size_t)t0 * 64);
    const int tot4 = nt * 16;
    float4* dstp = (float4*)sH;
    for (int i = tid; i < tot4; i += 256) dstp[i] = srcp[i];
  }
  __syncthreads();

  const int wave = tid >> 6, lane = tid & 63;
  const float* wcol = (lane < 32) ? (sWA + 4 * lane) : (sWB + 4 * (lane - 32));
  const int jj = (lane < 32) ? 4 * lane : 4 * (lane - 32);
  float* OUTb = (lane < 32) ? PA : PB;

  float4 acc[8];
#pragma unroll
  for (int i = 0; i < 8; ++i) acc[i] = make_float4(0.f, 0.f, 0.f, 0.f);

  for (int kc = 0; kc < 64; kc += 4) {
    const float4 w0 = *(const float4*)(wcol + (kc + 0) * 128);
    const float4 w1 = *(const float4*)(wcol + (kc + 1) * 128);
    const float4 w2 = *(const float4*)(wcol + (kc + 2) * 128);
    const float4 w3 = *(const float4*)(wcol + (kc + 3) * 128);
#pragma unroll
    for (int i = 0; i < 8; ++i) {
      const float4 a = *(const float4*)&sH[(wave * 8 + i) * 64 + kc];
      fma4(acc[i], a.x, w0);
      fma4(acc[i], a.y, w1);
      fma4(acc[i], a.z, w2);
      fma4(acc[i], a.w, w3);
    }
  }
#pragma unroll
  for (int i = 0; i < 8; ++i) {
    const int n = t0 + wave * 8 + i;
    if (n < N_NODES) *(float4*)&OUTb[(size_t)n * 128 + jj] = acc[i];
  }
}

// -------- tbl[t][128] = [ sum_k rbf(d_t,k)*Wi[128+k][:] | same for Wu ] ----
__global__ void k_tbl(const float* __restrict__ Wi_l,
                      const float* __restrict__ Wu_l,
                      float* __restrict__ tbl) {
  const int wave = threadIdx.x >> 6, lane = threadIdx.x & 63;
  const int t = blockIdx.x * (blockDim.x >> 6) + wave;
  if (t >= TBL) return;
  const float d = 8.0f * (float)t / (float)(TBL - 1);
  float gi_ = 0.f, gu_ = 0.f;
#pragma unroll
  for (int k = 0; k < 32; ++k) {
    const float c = 8.0f * (float)k / 31.0f;
    const float dd = d - c;
    const float r = expf(-3.875f * dd * dd);
    gi_ = fmaf(r, Wi_l[(128 + k) * 64 + lane], gi_);
    gu_ = fmaf(r, Wu_l[(128 + k) * 64 + lane], gu_);
  }
  tbl[(size_t)t * 128 + lane] = gi_;
  tbl[(size_t)t * 128 + 64 + lane] = gu_;
}

__device__ __forceinline__ void edge_pre(int e, int lane,
                                         const int* __restrict__ src,
                                         const int* __restrict__ dst,
                                         const float* __restrict__ bond,
                                         const float* __restrict__ PA,
                                         const float* __restrict__ PB,
                                         const float* __restrict__ tbl,
                                         float& yg, float& yu, int& dnode) {
  const int s = src[e];
  const int d2 = dst[e];
  const float d = bond[e];
  float f = d * ((float)(TBL - 1) / 8.0f);
  f = fminf(fmaxf(f, 0.0f), (float)(TBL - 1));
  int i0 = (int)f;
  if (i0 > TBL - 2) i0 = TBL - 2;
  const float fr = f - (float)i0;
  const float* ta = tbl + (size_t)i0 * 128 + lane;
  const float rg = fmaf(fr, ta[128] - ta[0], ta[0]);
  const float ru = fmaf(fr, ta[192] - ta[64], ta[64]);
  const float* pa = PA + (size_t)s * 128 + lane;
  const float* pb = PB + (size_t)d2 * 128 + lane;
  yg = pa[0] + pb[0] + rg;
  yu = pa[64] + pb[64] + ru;
  dnode = d2;
}

// Pass 1: column sums / sumsq of gate_pre and upd_pre over all edges.
__global__ void k_edge_stats(const int* __restrict__ src,
                             const int* __restrict__ dst,
                             const float* __restrict__ bond,
                             const float* __restrict__ PA,
                             const float* __restrict__ PB,
                             const float* __restrict__ tbl,
                             float* __restrict__ stats) {
  const int wave = threadIdx.x >> 6, lane = threadIdx.x & 63;
  const int wpb = blockDim.x >> 6;
  const int nw = wpb * gridDim.x;
  float sg = 0.f, qg = 0.f, su = 0.f, qu = 0.f;
  for (int e = blockIdx.x * wpb + wave; e < N_EDGES; e += nw) {
    float yg, yu; int dn;
    edge_pre(e, lane, src, dst, bond, PA, PB, tbl, yg, yu, dn);
    sg += yg; qg = fmaf(yg, yg, qg);
    su += yu; qu = fmaf(yu, yu, qu);
  }
  __shared__ float red[4][4][64];
  red[0][wave][lane] = sg;
  red[1][wave][lane] = qg;
  red[2][wave][lane] = su;
  red[3][wave][lane] = qu;
  __syncthreads();
  const float v = red[wave][0][lane] + red[wave][1][lane] +
                  red[wave][2][lane] + red[wave][3][lane];
  atomicAdd(&stats[wave * 64 + lane], v);
}

__global__ void k_fin_gu(const float* __restrict__ stats,
                         const float* __restrict__ gi_l, const float* __restrict__ bti_l,
                         const float* __restrict__ gu_l, const float* __restrict__ btu_l,
                         float* __restrict__ coefs) {
  const int j = threadIdx.x;
  const float invE = 1.0f / (float)N_EDGES;
  float m = stats[j] * invE;
  float v = stats[64 + j] * invE - m * m;
  float a = gi_l[j] * rsqrtf(v + EPSBN);
  coefs[j] = a;
  coefs[64 + j] = fmaf(-m, a, bti_l[j]);
  m = stats[128 + j] * invE;
  v = stats[192 + j] * invE - m * m;
  a = gu_l[j] * rsqrtf(v + EPSBN);
  coefs[128 + j] = a;
  coefs[192 + j] = fmaf(-m, a, btu_l[j]);
}

// Pass 2: recompute, apply BN+activations, scatter-add msg into agg[dst].
__global__ void k_edge_apply(const int* __restrict__ src,
                             const int* __restrict__ dst,
                             const float* __restrict__ bond,
                             const float* __restrict__ PA,
                             const float* __restrict__ PB,
                             const float* __restrict__ tbl,
                             const float* __restrict__ coefs,
                             float* __restrict__ agg) {
  const int wave = threadIdx.x >> 6, lane = threadIdx.x & 63;
  const int wpb = blockDim.x >> 6;
  const int nw = wpb * gridDim.x;
  const float ag = coefs[lane], bg = coefs[64 + lane];
  const float au = coefs[128 + lane], bu = coefs[192 + lane];
  for (int e = blockIdx.x * wpb + wave; e < N_EDGES; e += nw) {
    float yg, yu; int dn;
    edge_pre(e, lane, src, dst, bond, PA, PB, tbl, yg, yu, dn);
    const float gate = sigmoidf(fmaf(ag, yg, bg));
    const float upd = softplusf(fmaf(au, yu, bu));
    atomicAdd(&agg[(size_t)dn * 64 + lane], gate * upd);
  }
}

__global__ void k_agg_stats(const float* __restrict__ agg, float* __restrict__ stats) {
  const int wave = threadIdx.x >> 6, lane = threadIdx.x & 63;
  const int wpb = blockDim.x >> 6;
  const int nw = wpb * gridDim.x;
  float s = 0.f, q = 0.f;
  for (int n = blockIdx.x * wpb + wave; n < N_NODES; n += nw) {
    const float v = agg[(size_t)n * 64 + lane];
    s += v; q = fmaf(v, v, q);
  }
  __shared__ float red[2][4][64];
  red[0][wave][lane] = s;
  red[1][wave][lane] = q;
  __syncthreads();
  if (wave < 2) {
    const float v = red[wave][0][lane] + red[wave][1][lane] +
                    red[wave][2][lane] + red[wave][3][lane];
    atomicAdd(&stats[256 + wave * 64 + lane], v);
  }
}

__global__ void k_fin_agg(const float* __restrict__ stats,
                          const float* __restrict__ gbn_l, const float* __restrict__ bbn_l,
                          float* __restrict__ coefs) {
  const int j = threadIdx.x;
  const float invN = 1.0f / (float)N_NODES;
  const float m = stats[256 + j] * invN;
  const float v = stats[320 + j] * invN - m * m;
  const float a = gbn_l[j] * rsqrtf(v + EPSBN);
  coefs[256 + j] = a;
  coefs[320 + j] = fmaf(-m, a, bbn_l[j]);
}

// h = softplus(h + BN(agg))
__global__ void k_hupd(float* __restrict__ h, const float* __restrict__ agg,
                       const float* __restrict__ coefs) {
  const int stride = blockDim.x * gridDim.x;
  for (int i = blockIdx.x * blockDim.x + threadIdx.x; i < N_NODES * 64; i += stride) {
    const int j = i & 63;
    const float x = h[i] + fmaf(coefs[256 + j], agg[i], coefs[320 + j]);
    h[i] = softplusf(x);
  }
}

__global__ void k_pool(const float* __restrict__ h, const int* __restrict__ gid,
                       float* __restrict__ pooled, float* __restrict__ counts) {
  const int wave = threadIdx.x >> 6, lane = threadIdx.x & 63;
  const int wpb = blockDim.x >> 6;
  const int nw = wpb * gridDim.x;
  for (int n = blockIdx.x * wpb + wave; n < N_NODES; n += nw) {
    const int g = gid[n];
    atomicAdd(&pooled[(size_t)g * 64 + lane], h[(size_t)n * 64 + lane]);
    if (lane == 0) atomicAdd(&counts[g], 1.0f);
  }
}

__global__ void k_final(const float* __restrict__ pooled, const float* __restrict__ counts,
                        const float* __restrict__ Wfc, const float* __restrict__ bfc,
                        const float* __restrict__ Wout, const float* __restrict__ bout,
                        float* __restrict__ out) {
  __shared__ float f1[64];
  __shared__ float red[128];
  const int g = blockIdx.x, t = threadIdx.x;
  if (t < 64) {
    const float c = fmaxf(counts[g], 1.0f);
    f1[t] = softplusf(pooled[(size_t)g * 64 + t] / c);
  }
  __syncthreads();
  float acc = bfc[t];
#pragma unroll
  for (int k = 0; k < 64; ++k) acc = fmaf(f1[k], Wfc[k * 128 + t], acc);
  red[t] = softplusf(softplusf(acc)) * Wout[t];
  __syncthreads();
  for (int s2 = 64; s2 > 0; s2 >>= 1) {
    if (t < s2) red[t] += red[t + s2];
    __syncthreads();
  }
  if (t == 0) out[g] = red[0] + bout[0];
}

extern "C" void kernel_launch(void* const* d_in, const int* in_sizes, int n_in,
                              void* d_out, int out_size, void* d_ws, size_t ws_size,
                              hipStream_t stream) {
  const float* atom = (const float*)d_in[0];
  const float* bond = (const float*)d_in[1];
  const int* src = (const int*)d_in[2];
  const int* dst = (const int*)d_in[3];
  const int* gid = (const int*)d_in[4];
  const float* Wemb = (const float*)d_in[5];
  const float* bemb = (const float*)d_in[6];
  const float* Wi = (const float*)d_in[7];
  // d_in[8] = bi  — cancels under BN (mean-shift), unused
  const float* gi = (const float*)d_in[9];
  const float* bti = (const float*)d_in[10];
  const float* Wu = (const float*)d_in[11];
  // d_in[12] = bu — cancels under BN, unused
  const float* gub = (const float*)d_in[13];
  const float* btu = (const float*)d_in[14];
  const float* gbn = (const float*)d_in[15];
  const float* bbn = (const float*)d_in[16];
  const float* Wfc = (const float*)d_in[17];
  const float* bfc = (const float*)d_in[18];
  const float* Wout = (const float*)d_in[19];
  const float* bout = (const float*)d_in[20];

  // workspace (floats): h N*64 | PA N*128 | PB N*128 | agg N*64 | tbl TBL*128
  //                     | stats 384 | coefs 384 | pooled G*64 | counts G
  float* h = (float*)d_ws;
  float* PA = h + (size_t)N_NODES * 64;
  float* PB = PA + (size_t)N_NODES * 128;
  float* agg = PB + (size_t)N_NODES * 128;
  float* tbl = agg + (size_t)N_NODES * 64;
  float* stats = tbl + (size_t)TBL * 128;
  float* coefs = stats + 384;
  float* pooled = coefs + 384;
  float* counts = pooled + (size_t)N_GRAPHS * 64;

  const int ntiles = (N_NODES + 31) / 32;  // 1563

  k_emb<<<ntiles, 256, 0, stream>>>(atom, Wemb, bemb, h);
  for (int l = 0; l < 3; ++l) {
    const float* Wi_l = Wi + (size_t)l * 160 * 64;
    const float* Wu_l = Wu + (size_t)l * 160 * 64;
    (void)hipMemsetAsync(stats, 0, 384 * sizeof(float), stream);
    (void)hipMemsetAsync(agg, 0, (size_t)N_NODES * 64 * sizeof(float), stream);
    k_pq<<<ntiles, 256, 0, stream>>>(h, Wi_l, Wu_l, PA, PB);
    k_tbl<<<TBL / 4, 256, 0, stream>>>(Wi_l, Wu_l, tbl);
    k_edge_stats<<<2048, 256, 0, stream>>>(src, dst, bond, PA, PB, tbl, stats);
    k_fin_gu<<<1, 64, 0, stream>>>(stats, gi + l * 64, bti + l * 64,
                                   gub + l * 64, btu + l * 64, coefs);
    k_edge_apply<<<2048, 256, 0, stream>>>(src, dst, bond, PA, PB, tbl, coefs, agg);
    k_agg_stats<<<512, 256, 0, stream>>>(agg, stats);
    k_fin_agg<<<1, 64, 0, stream>>>(stats, gbn + l * 64, bbn + l * 64, coefs);
    k_hupd<<<1024, 256, 0, stream>>>(h, agg, coefs);
  }
  (void)hipMemsetAsync(pooled, 0, (size_t)(N_GRAPHS * 64 + N_GRAPHS) * sizeof(float), stream);
  k_pool<<<512, 256, 0, stream>>>(h, gid, pooled, counts);
  k_final<<<N_GRAPHS, 128, 0, stream>>>(pooled, counts, Wfc, bfc, Wout, bout,
                                        (float*)d_out);
}